// Round 2
// baseline (165.941 us; speedup 1.0000x reference)
//
#include <hip/hip_runtime.h>
#include <math.h>

#define NT 512      // 8 waves, single block, single CU
#define EPT 8       // NT*EPT = 4096
#define NN 4096
#define MM 9
#define NIT 50

// geometric carry weights (per-thread hop decay 2^-8)
#define W256_1 3.90625e-3f
#define W256_2 1.52587890625e-5f
#define W256_3 5.9604644775390625e-8f
#define K1LAST 0.3333282470703125f

// ---------- setup-only: 2-barrier LDS tree reduce of 9 partials ----------
__device__ __forceinline__ void block_reduce9(const float pq[MM], float* __restrict__ s_part,
                                              float* __restrict__ dest, int destStride,
                                              int identCol, int t) {
#pragma unroll
  for (int m = 0; m < MM; ++m) s_part[m * NT + t] = pq[m];
  __syncthreads();
  const int wave = t >> 6, lane = t & 63;
  for (int m = wave; m < MM; m += NT / 64) {
    float s = 0.f;
#pragma unroll
    for (int k = 0; k < NT / 64; ++k) s += s_part[m * NT + lane + 64 * k];
#pragma unroll
    for (int off = 32; off; off >>= 1) s += __shfl_xor(s, off, 64);
    if (lane == 0) dest[m * destStride] = s + ((m == identCol) ? 1.f : 0.f);
  }
  __syncthreads();
}

// ---------- single-barrier cyclic tridiagonal solve: M p = r ----------
// M = 25I - 10(P+P^T) = 5(2I-S+)(2I-S-). Both scan carries reconstructed after
// ONE barrier: store (yl0, pl0_last); forward carry's dependence on backward
// carry is linear with constants K1[j]. Truncation ~2^-32.
__device__ __forceinline__ void solveM_fused(const float r[EPT], float p[EPT],
                                             float2* __restrict__ s_sc, int t) {
  const float K1[EPT] = {0.001953125f, 0.0048828125f, 0.01025390625f, 0.020751953125f,
                         0.0416259765625f, 0.08331298828125f, 0.166656494140625f,
                         0.3333282470703125f};
  float yl[EPT];
  yl[EPT - 1] = r[EPT - 1] * 0.1f;
#pragma unroll
  for (int j = EPT - 2; j >= 0; --j) yl[j] = fmaf(0.5f, yl[j + 1], r[j] * 0.1f);
  float pl0[EPT];
  pl0[0] = 0.5f * yl[0];
#pragma unroll
  for (int j = 1; j < EPT; ++j) pl0[j] = 0.5f * (yl[j] + pl0[j - 1]);
  s_sc[t] = make_float2(yl[0], pl0[EPT - 1]);
  __syncthreads();
  float2 g[9];
#pragma unroll
  for (int k = 0; k < 9; ++k) g[k] = s_sc[(t + k - 4) & (NT - 1)];
  // backward carry c_t = sum_i 256^-i * yl0[t+1+i]
  float c = fmaf(W256_3, g[8].x, fmaf(W256_2, g[7].x, fmaf(W256_1, g[6].x, g[5].x)));
  // forward carry c2_t = sum_j 256^-j * pl0last[t-1-j] + K1LAST * sum_k 256^-|k| * yl0[t+k]
  float s1 = fmaf(W256_3, g[0].y, fmaf(W256_2, g[1].y, fmaf(W256_1, g[2].y, g[3].y)));
  float s2 = g[4].x;
  s2 = fmaf(W256_1, g[3].x + g[5].x, s2);
  s2 = fmaf(W256_2, g[2].x + g[6].x, s2);
  s2 = fmaf(W256_3, g[1].x + g[7].x, s2);
  float c2 = fmaf(K1LAST, s2, s1);
  float f2 = 0.5f;
#pragma unroll
  for (int j = 0; j < EPT; ++j) {
    p[j] = fmaf(c2, f2, fmaf(c, K1[j], pl0[j]));
    f2 *= 0.5f;
  }
}

__global__ void __launch_bounds__(NT, 2)
admm_kernel(const float* __restrict__ tg, const float* __restrict__ Ag,
            const float* __restrict__ x0, float* __restrict__ out) {
  __shared__ float s_x[NN];
  __shared__ float s_part[MM * NT];   // setup only
  __shared__ float2 s_sc[NT];
  __shared__ float2 s_sc2[NT];        // setup ping-pong
  __shared__ float s_wq[8][12];       // per-wave q sums (padded to 12 for float4)
  __shared__ float s_q[MM];
  __shared__ float s_S[MM * MM];
  __shared__ float s_Sinv[MM * MM];

  const int t = threadIdx.x;
  const int base = t * EPT;
  const int lane = t & 63, wave = t >> 6;

  // ---- load A slice ----
  float A[MM][EPT];
#pragma unroll
  for (int m = 0; m < MM; ++m) {
    float4 a0 = *(const float4*)(Ag + m * NN + base);
    float4 a1 = *(const float4*)(Ag + m * NN + base + 4);
    A[m][0] = a0.x; A[m][1] = a0.y; A[m][2] = a0.z; A[m][3] = a0.w;
    A[m][4] = a1.x; A[m][5] = a1.y; A[m][6] = a1.z; A[m][7] = a1.w;
  }

  // ---- load x0, target ----
  float x[EPT], tgt[EPT];
  {
    float4 v0 = *(const float4*)(x0 + base);
    float4 v1 = *(const float4*)(x0 + base + 4);
    x[0] = v0.x; x[1] = v0.y; x[2] = v0.z; x[3] = v0.w;
    x[4] = v1.x; x[5] = v1.y; x[6] = v1.z; x[7] = v1.w;
    float4 t0 = *(const float4*)(tg + base);
    float4 t1 = *(const float4*)(tg + base + 4);
    tgt[0] = t0.x; tgt[1] = t0.y; tgt[2] = t0.z; tgt[3] = t0.w;
    tgt[4] = t1.x; tgt[5] = t1.y; tgt[6] = t1.z; tgt[7] = t1.w;
  }
#pragma unroll
  for (int j = 0; j < EPT; ++j) s_x[base + j] = x[j];

  // ---- b = A @ target ----
  float pq[MM];
#pragma unroll
  for (int m = 0; m < MM; ++m) {
    float s = 0.f;
#pragma unroll
    for (int j = 0; j < EPT; ++j) s = fmaf(A[m][j], tgt[j], s);
    pq[m] = s;
  }
  block_reduce9(pq, s_part, s_q, 1, -1, t);

  // ---- bA = b @ A ----
  float bA[EPT];
  {
    float bv[MM];
#pragma unroll
    for (int m = 0; m < MM; ++m) bv[m] = s_q[m];
#pragma unroll
    for (int j = 0; j < EPT; ++j) {
      float s = 0.f;
#pragma unroll
      for (int m = 0; m < MM; ++m) s = fmaf(bv[m], A[m][j], s);
      bA[j] = s;
    }
  }

  // ---- G = M^-1 A^T (ping-pong buffers between back-to-back solves) ----
  float G[MM][EPT];
#pragma unroll
  for (int m = 0; m < MM; ++m) {
    float rin[EPT], pcol[EPT];
#pragma unroll
    for (int j = 0; j < EPT; ++j) rin[j] = A[m][j];
    solveM_fused(rin, pcol, (m & 1) ? s_sc2 : s_sc, t);
#pragma unroll
    for (int j = 0; j < EPT; ++j) G[m][j] = pcol[j];
  }

  // ---- S = I9 + A G ----
#pragma unroll 1
  for (int mcol = 0; mcol < MM; ++mcol) {
#pragma unroll
    for (int k = 0; k < MM; ++k) {
      float s = 0.f;
#pragma unroll
      for (int j = 0; j < EPT; ++j) s = fmaf(A[k][j], G[mcol][j], s);
      pq[k] = s;
    }
    block_reduce9(pq, s_part, &s_S[mcol], MM, mcol, t);
  }

  // ---- Sinv via wave-parallel Gauss-Jordan (lanes 0..8 of wave 0) ----
  if (t < 64) {
    float row[2 * MM];
#pragma unroll
    for (int j = 0; j < MM; ++j) row[j] = (t < MM) ? s_S[t * MM + j] : 0.f;
#pragma unroll
    for (int j = 0; j < MM; ++j) row[MM + j] = (j == t) ? 1.f : 0.f;
#pragma unroll
    for (int pp = 0; pp < MM; ++pp) {
      float pr[2 * MM];
#pragma unroll
      for (int j = 0; j < 2 * MM; ++j) pr[j] = __shfl(row[j], pp, 64);
      float rpiv = 1.f / pr[pp];
      float fct = row[pp] * rpiv;
#pragma unroll
      for (int j = 0; j < 2 * MM; ++j)
        row[j] = (t == pp) ? pr[j] * rpiv : fmaf(-fct, pr[j], row[j]);
    }
    if (t < MM) {
#pragma unroll
      for (int j = 0; j < MM; ++j) s_Sinv[t * MM + j] = row[MM + j];
    }
  }
  __syncthreads();

  // ---- fold Sinv into G in place: G[m][j] <- sum_k G[k][j] * Sinv[k][m] ----
  // (then x_new = p - G q directly; no z matvec, no z barrier in the loop)
#pragma unroll
  for (int j = 0; j < EPT; ++j) {
    float tmp[MM];
#pragma unroll
    for (int k = 0; k < MM; ++k) tmp[k] = G[k][j];
#pragma unroll
    for (int m = 0; m < MM; ++m) {
      float s = 0.f;
#pragma unroll
      for (int k = 0; k < MM; ++k) s = fmaf(s_Sinv[k * MM + m], tmp[k], s);
      G[m][j] = s;
    }
  }

  // ---- ADMM iterations: 3 barriers each ----
  float eta[EPT], tau[EPT];
#pragma unroll
  for (int j = 0; j < EPT; ++j) { eta[j] = 0.f; tau[j] = 0.f; }

#pragma unroll 1
  for (int it = 0; it < NIT; ++it) {
    float xm1 = s_x[(base + NN - 1) & (NN - 1)];
    float u[EPT], w[EPT], r[EPT];
#pragma unroll
    for (int j = 0; j < EPT; ++j) {
      float xprev = (j == 0) ? xm1 : x[j - 1];
      float v = xprev - x[j] + eta[j] * 0.1f;
      float a = fabsf(v) - 1e-5f;
      u[j] = (a > 0.f) ? copysignf(a, v) : 0.f;
      w[j] = fmaxf(fmaf(tau[j], 0.2f, x[j]), 0.f);
      r[j] = bA[j] + 10.f * u[j] - eta[j] + 5.f * w[j] - tau[j];
    }
    // p = M^-1 r            (barrier 1 inside)
    float p[EPT];
    solveM_fused(r, p, s_sc, t);
    // per-thread q partials
#pragma unroll
    for (int m = 0; m < MM; ++m) {
      float s = 0.f;
#pragma unroll
      for (int j = 0; j < EPT; ++j) s = fmaf(A[m][j], p[j], s);
      pq[m] = s;
    }
    // in-wave butterfly (no barrier)
#pragma unroll
    for (int off = 32; off; off >>= 1) {
#pragma unroll
      for (int m = 0; m < MM; ++m) pq[m] += __shfl_xor(pq[m], off, 64);
    }
    if (lane == 0) {
#pragma unroll
      for (int m = 0; m < MM; ++m) s_wq[wave][m] = pq[m];
    }
    __syncthreads();   // barrier 2
    // q totals: broadcast reads of 8 per-wave sums
    float q[MM];
    {
      float4 a0 = *(const float4*)&s_wq[0][0];
      float4 a1 = *(const float4*)&s_wq[0][4];
      float  a2 = s_wq[0][8];
      q[0] = a0.x; q[1] = a0.y; q[2] = a0.z; q[3] = a0.w;
      q[4] = a1.x; q[5] = a1.y; q[6] = a1.z; q[7] = a1.w; q[8] = a2;
#pragma unroll
      for (int wv = 1; wv < 8; ++wv) {
        float4 b0 = *(const float4*)&s_wq[wv][0];
        float4 b1 = *(const float4*)&s_wq[wv][4];
        float  b2 = s_wq[wv][8];
        q[0] += b0.x; q[1] += b0.y; q[2] += b0.z; q[3] += b0.w;
        q[4] += b1.x; q[5] += b1.y; q[6] += b1.z; q[7] += b1.w; q[8] += b2;
      }
    }
    // x_new = p - (G Sinv) q
    float xn[EPT];
#pragma unroll
    for (int j = 0; j < EPT; ++j) {
      float s = p[j];
#pragma unroll
      for (int m = 0; m < MM; ++m) s = fmaf(-G[m][j], q[m], s);
      xn[j] = s;
    }
#pragma unroll
    for (int j = 0; j < EPT; ++j) s_x[base + j] = xn[j];
    __syncthreads();   // barrier 3
    float xnext = s_x[(base + EPT) & (NN - 1)];
#pragma unroll
    for (int j = 0; j < EPT; ++j) {
      float d = ((j == EPT - 1) ? xnext : xn[j + 1]) - xn[j];
      eta[j] = fmaf(10.f, d - u[j], eta[j]);
      tau[j] = fmaf(5.f, xn[j] - w[j], tau[j]);
      x[j] = xn[j];
    }
  }

  // ---- output ----
  float4 o0, o1;
  o0.x = x[0]; o0.y = x[1]; o0.z = x[2]; o0.w = x[3];
  o1.x = x[4]; o1.y = x[5]; o1.z = x[6]; o1.w = x[7];
  *(float4*)(out + base) = o0;
  *(float4*)(out + base + 4) = o1;
}

extern "C" void kernel_launch(void* const* d_in, const int* in_sizes, int n_in,
                              void* d_out, int out_size, void* d_ws, size_t ws_size,
                              hipStream_t stream) {
  const float* target = (const float*)d_in[0];
  const float* A      = (const float*)d_in[1];
  const float* x0     = (const float*)d_in[2];
  admm_kernel<<<1, NT, 0, stream>>>(target, A, x0, (float*)d_out);
}